// Round 12
// baseline (289.494 us; speedup 1.0000x reference)
//
#include <hip/hip_runtime.h>
#include <hip/hip_bf16.h>

#define NN 50000
#define NE 600000
#define SCAN_BLOCKS 196   // ceil(50000/256)

typedef __attribute__((ext_vector_type(8))) short short8v;   // 8 bf16 = 4 VGPRs
typedef __attribute__((ext_vector_type(4))) float float4v;   // MFMA C/D

// Dataset facts (pinned on HW over R3-R8): floats fp32, edges int32, out fp32.
__device__ __forceinline__ float bf2f_u(unsigned short u) {
    union { unsigned int i; float f; } v; v.i = ((unsigned int)u) << 16; return v.f;
}
__device__ __forceinline__ unsigned short f2bf_u(float f) {
    __hip_bfloat16 b = __float2bfloat16(f);
    return *reinterpret_cast<unsigned short*>(&b);
}

// ---------------------------------------------------------------------------
// CSR count (+ folded W-prep in the tail blocks).
// prep: fp32 W[k][n] -> bf16 Wt[n][k]; kills scalar ds_writes in GEMM (R11).
// ---------------------------------------------------------------------------
__global__ __launch_bounds__(256) void csr_count_prep(const int* __restrict__ ei,
                                                      int* __restrict__ cnt,
                                                      const float* __restrict__ W1,
                                                      const float* __restrict__ W2,
                                                      unsigned short* __restrict__ wt1,
                                                      unsigned short* __restrict__ wt2,
                                                      int edgeBlocks) {
    if ((int)blockIdx.x >= edgeBlocks) {   // W-prep tail: 128 blocks
        int t = (blockIdx.x - edgeBlocks) * 256 + threadIdx.x;   // 0..32767
        const float* src = (t < 16384) ? W1 : W2;
        unsigned short* dst = (t < 16384) ? wt1 : wt2;
        int idx = t & 16383;
        int n = idx >> 7, k = idx & 127;
        dst[idx] = f2bf_u(src[k * 128 + n]);
        return;
    }
    int e = blockIdx.x * 256 + threadIdx.x;
    if (e >= NE) return;
    int d = ei[NE + e];
    d = min(max(d, 0), NN - 1);
    atomicAdd(&cnt[d], 1);
}

__global__ __launch_bounds__(256) void scan_blocks(const int* __restrict__ cnt,
                                                   int* __restrict__ off,
                                                   int* __restrict__ bsum) {
    __shared__ int tmp[256];
    const int t = threadIdx.x;
    int g = blockIdx.x * 256 + t;
    int v = (g < NN) ? cnt[g] : 0;
    tmp[t] = v;
    __syncthreads();
    for (int ofs = 1; ofs < 256; ofs <<= 1) {
        int add = (t >= ofs) ? tmp[t - ofs] : 0;
        __syncthreads();
        tmp[t] += add;
        __syncthreads();
    }
    if (g < NN) off[g] = tmp[t] - v;          // block-local exclusive
    if (t == 255) bsum[blockIdx.x] = tmp[255];
}

__global__ __launch_bounds__(256) void scan_bsums(int* __restrict__ bsum,
                                                  int* __restrict__ bpre,
                                                  int* __restrict__ offNN) {
    __shared__ int tmp[256];
    const int t = threadIdx.x;
    int v = (t < SCAN_BLOCKS) ? bsum[t] : 0;
    tmp[t] = v;
    __syncthreads();
    for (int ofs = 1; ofs < 256; ofs <<= 1) {
        int add = (t >= ofs) ? tmp[t - ofs] : 0;
        __syncthreads();
        tmp[t] += add;
        __syncthreads();
    }
    if (t < SCAN_BLOCKS) bpre[t] = tmp[t] - v;
    if (t == 255) *offNN = tmp[255];          // = NE
}

__global__ __launch_bounds__(256) void scan_add(int* __restrict__ off,
                                                const int* __restrict__ bpre,
                                                int* __restrict__ cursor) {
    int g = blockIdx.x * 256 + threadIdx.x;
    if (g >= NN) return;
    int o = off[g] + bpre[blockIdx.x];
    off[g] = o;
    cursor[g] = o;
}

__global__ __launch_bounds__(256) void csr_fill(const int* __restrict__ ei,
                                                int* __restrict__ cursor,
                                                int* __restrict__ csrc) {
    int e = blockIdx.x * 256 + threadIdx.x;
    if (e >= NE) return;
    int s = ei[e], d = ei[NE + e];
    s = min(max(s, 0), NN - 1);
    d = min(max(d, 0), NN - 1);
    int pos = atomicAdd(&cursor[d], 1);
    csrc[pos] = s;
}

// ---------------------------------------------------------------------------
// MFMA bf16 GEMM + fused attention-logit epilogue (R11, unchanged).
// H[n x 128](bf16) = X @ Wt^T; Wt pre-transposed bf16 [n][k].
// XF32=1: X fp32 (layer1), convert during staging; 0: X bf16 (x2).
// C/D layout (m97): col=ct*16+m, row=wrow+q*4+r; head=ct>>1 for H=4.
// ---------------------------------------------------------------------------
template<int H, int XF32>
__global__ __launch_bounds__(256) void gemm_fused(const void* __restrict__ X,
                                                  const unsigned short* __restrict__ Wt,
                                                  const float* __restrict__ a_src,
                                                  const float* __restrict__ a_dst,
                                                  unsigned short* __restrict__ Hout,
                                                  float* __restrict__ als,
                                                  float* __restrict__ ald, int n) {
    __shared__ unsigned short Xs[64][136];
    __shared__ unsigned short WtS[128][136];
    __shared__ float as_s[128], ad_s[128];
    const int tid = threadIdx.x;
    const int row0 = blockIdx.x * 64;

    if (tid < 128) { as_s[tid] = a_src[tid]; ad_s[tid] = a_dst[tid]; }
    {   // stage pre-transposed Wt: pure uint4 copies
        const uint4* Wv = (const uint4*)Wt;
#pragma unroll
        for (int i = 0; i < 8; ++i) {
            int lin = tid + 256 * i;              // 0..2047
            int r = lin >> 4, c8 = lin & 15;
            *(uint4*)&WtS[r][c8 * 8] = Wv[lin];
        }
    }
    if (XF32) {
        const float4* Xv = (const float4*)X;
#pragma unroll
        for (int i = 0; i < 8; ++i) {
            int lin = tid + 256 * i;
            int r = lin >> 5, c4 = lin & 31;
            float4 v = make_float4(0.f, 0.f, 0.f, 0.f);
            if (row0 + r < n) v = Xv[(size_t)(row0 + r) * 32 + c4];
            ushort4 o;
            o.x = f2bf_u(v.x); o.y = f2bf_u(v.y); o.z = f2bf_u(v.z); o.w = f2bf_u(v.w);
            *(ushort4*)&Xs[r][c4 * 4] = o;
        }
    } else {
        const uint4* Xv = (const uint4*)X;
#pragma unroll
        for (int i = 0; i < 4; ++i) {
            int lin = tid + 256 * i;
            int r = lin >> 4, c8 = lin & 15;
            uint4 v = make_uint4(0u, 0u, 0u, 0u);
            if (row0 + r < n) v = Xv[(size_t)(row0 + r) * 16 + c8];
            *(uint4*)&Xs[r][c8 * 8] = v;
        }
    }
    __syncthreads();

    const int lane = tid & 63;
    const int wrow = (tid >> 6) * 16;
    const int m = lane & 15, q = lane >> 4;

    float4v acc[8];
#pragma unroll
    for (int ct = 0; ct < 8; ++ct) acc[ct] = (float4v){0.f, 0.f, 0.f, 0.f};

#pragma unroll
    for (int kt = 0; kt < 4; ++kt) {
        short8v af = *(const short8v*)&Xs[wrow + m][kt * 32 + q * 8];
#pragma unroll
        for (int ct = 0; ct < 8; ++ct) {
            short8v bf = *(const short8v*)&WtS[ct * 16 + m][kt * 32 + q * 8];
            acc[ct] = __builtin_amdgcn_mfma_f32_16x16x32_bf16(af, bf, acc[ct], 0, 0, 0);
        }
    }

    // store H (bf16)
#pragma unroll
    for (int ct = 0; ct < 8; ++ct)
#pragma unroll
        for (int r = 0; r < 4; ++r) {
            int grow = row0 + wrow + q * 4 + r;
            if (grow < n) Hout[(size_t)grow * 128 + ct * 16 + m] = f2bf_u(acc[ct][r]);
        }

    // fused als/ald epilogue (fp32 accumulators)
#pragma unroll
    for (int r = 0; r < 4; ++r) {
        int grow = row0 + wrow + q * 4 + r;
        if (H == 4) {
            float ps[4], pd[4];
#pragma unroll
            for (int hd = 0; hd < 4; ++hd) {
                float x0 = acc[2 * hd][r], x1 = acc[2 * hd + 1][r];
                ps[hd] = x0 * as_s[hd * 32 + m] + x1 * as_s[hd * 32 + 16 + m];
                pd[hd] = x0 * ad_s[hd * 32 + m] + x1 * ad_s[hd * 32 + 16 + m];
#pragma unroll
                for (int o = 1; o < 16; o <<= 1) {
                    ps[hd] += __shfl_xor(ps[hd], o);
                    pd[hd] += __shfl_xor(pd[hd], o);
                }
            }
            if (m == 0 && grow < n) {
#pragma unroll
                for (int hd = 0; hd < 4; ++hd) {
                    als[(size_t)grow * 4 + hd] = ps[hd];
                    ald[(size_t)grow * 4 + hd] = pd[hd];
                }
            }
        } else {
            float ps = 0.f, pd = 0.f;
#pragma unroll
            for (int ct = 0; ct < 8; ++ct) {
                float xv = acc[ct][r];
                ps += xv * as_s[ct * 16 + m];
                pd += xv * ad_s[ct * 16 + m];
            }
#pragma unroll
            for (int o = 1; o < 16; o <<= 1) {
                ps += __shfl_xor(ps, o);
                pd += __shfl_xor(pd, o);
            }
            if (m == 0 && grow < n) { als[grow] = ps; ald[grow] = pd; }
        }
    }
}

// ---------------------------------------------------------------------------
// Fused aggregate, TWO waves per dst node (R12): halves the serial batch
// depth (deg~13: 2 gather rounds -> 1). Block = 256 thr = 4 waves = 2 nodes;
// NN=50000 even -> grid 25000 full blocks, no partial-block sync hazard.
// Each half-wave processes interleaved edges (shares csrc cache lines),
// 4-edge batched gathers; halves combine via LDS (stride-3 -> conflict-free).
// FINAL=0: +bias, ELU, bf16 x2 out. FINAL=1: +bias, fp32 out. No atomics.
// ---------------------------------------------------------------------------
template<int H, int FINAL>
__global__ __launch_bounds__(256) void aggregate(const int* __restrict__ off,
                                                 const int* __restrict__ csrc,
                                                 const unsigned short* __restrict__ h,
                                                 const float* __restrict__ als,
                                                 const float* __restrict__ ald,
                                                 const float* __restrict__ bias,
                                                 void* __restrict__ out) {
    __shared__ float part[2][64][3];
    const int lane = threadIdx.x & 63;
    const int ns   = (threadIdx.x >> 7) & 1;          // node slot in block
    const int half = (threadIdx.x >> 6) & 1;          // which wave of the pair
    const int d = blockIdx.x * 2 + ns;
    const int hd = (H == 4) ? (lane >> 4) : 0;
    const float aldd = (H == 4) ? ald[(size_t)d * 4 + hd] : ald[d];

    float acc0 = 0.f, acc1 = 0.f, den = 0.f;
    auto doEdge = [&](float av, unsigned int hv) {
        float v = av + aldd;
        v = v > 0.f ? v : 0.2f * v;
        float ex = __expf(fminf(v, 60.f));
        acc0 += ex * bf2f_u((unsigned short)hv);
        acc1 += ex * bf2f_u((unsigned short)(hv >> 16));
        den += ex;
    };

    if (half == 0) {   // self-loop once
        float av = (H == 4) ? als[(size_t)d * 4 + hd] : als[d];
        unsigned int hv = *(const unsigned int*)&h[(size_t)d * 128 + lane * 2];
        doEdge(av, hv);
    }
    int j = off[d] + half;
    const int end = off[d + 1];
    for (; j + 6 < end; j += 8) {        // 4 edges per round, stride 2
        int s0 = csrc[j], s1 = csrc[j + 2], s2 = csrc[j + 4], s3 = csrc[j + 6];
        unsigned int h0 = *(const unsigned int*)&h[(size_t)s0 * 128 + lane * 2];
        unsigned int h1 = *(const unsigned int*)&h[(size_t)s1 * 128 + lane * 2];
        unsigned int h2 = *(const unsigned int*)&h[(size_t)s2 * 128 + lane * 2];
        unsigned int h3 = *(const unsigned int*)&h[(size_t)s3 * 128 + lane * 2];
        float a0 = (H == 4) ? als[(size_t)s0 * 4 + hd] : als[s0];
        float a1 = (H == 4) ? als[(size_t)s1 * 4 + hd] : als[s1];
        float a2 = (H == 4) ? als[(size_t)s2 * 4 + hd] : als[s2];
        float a3 = (H == 4) ? als[(size_t)s3 * 4 + hd] : als[s3];
        doEdge(a0, h0); doEdge(a1, h1); doEdge(a2, h2); doEdge(a3, h3);
    }
    for (; j < end; j += 2) {
        int s = csrc[j];
        unsigned int hv = *(const unsigned int*)&h[(size_t)s * 128 + lane * 2];
        float av = (H == 4) ? als[(size_t)s * 4 + hd] : als[s];
        doEdge(av, hv);
    }

    // combine halves via LDS
    if (half == 1) {
        part[ns][lane][0] = acc0;
        part[ns][lane][1] = acc1;
        part[ns][lane][2] = den;
    }
    __syncthreads();
    if (half == 1) return;
    acc0 += part[ns][lane][0];
    acc1 += part[ns][lane][1];
    den  += part[ns][lane][2];

    const float inv = 1.f / den;
    const int c0 = lane * 2;
    float v0 = acc0 * inv + bias[c0];
    float v1 = acc1 * inv + bias[c0 + 1];
    if (FINAL) {
        ((float2*)out)[(size_t)d * 64 + lane] = make_float2(v0, v1);   // fp32 out
    } else {
        v0 = v0 > 0.f ? v0 : expm1f(v0);
        v1 = v1 > 0.f ? v1 : expm1f(v1);
        unsigned int packed = (unsigned int)f2bf_u(v0) | ((unsigned int)f2bf_u(v1) << 16);
        ((unsigned int*)out)[(size_t)d * 64 + lane] = packed;
    }
}

// ---------------------------------------------------------------------------
extern "C" void kernel_launch(void* const* d_in, const int* in_sizes, int n_in,
                              void* d_out, int out_size, void* d_ws, size_t ws_size,
                              hipStream_t stream) {
    const float* x      = (const float*)d_in[0];
    const int*   ei     = (const int*)d_in[1];
    const float* W1     = (const float*)d_in[2];
    const float* a_src1 = (const float*)d_in[3];
    const float* a_dst1 = (const float*)d_in[4];
    const float* b1     = (const float*)d_in[5];
    const float* W2     = (const float*)d_in[6];
    const float* a_src2 = (const float*)d_in[7];
    const float* a_dst2 = (const float*)d_in[8];
    const float* b2     = (const float*)d_in[9];

    const int N = NN;

    // Workspace: explicit BYTE offsets, every buffer 16B-aligned.
    char* base = (char*)d_ws;
    int*   cnt    = (int*)(base + 0);          //  50000 i
    int*   off    = (int*)(base + 200000);     //  50001 i
    int*   cursor = (int*)(base + 400016);     //  50000 i
    int*   bsum   = (int*)(base + 600016);     //    256 i
    int*   bpre   = (int*)(base + 601040);     //    256 i
    int*   csrc   = (int*)(base + 602064);     // 600000 i
    float* als    = (float*)(base + 3002064);  // 200000 f
    float* ald    = (float*)(base + 3802064);  // 200000 f
    unsigned short* h   = (unsigned short*)(base + 4602064);   // N*128 bf16
    unsigned short* x2  = (unsigned short*)(base + 17402064);  // N*128 bf16
    unsigned short* wt1 = (unsigned short*)(base + 30202064);  // 16384 bf16
    unsigned short* wt2 = (unsigned short*)(base + 30234832);  // 16384 bf16
    // total 30,267,600 B ~= 30.3 MB

    const int gemmGrid = (N + 63) / 64;          // 782
    const int edgeGrid = (NE + 255) / 256;       // 2344
    const int aggGrid  = N / 2;                  // 25000 (2 nodes/block, exact)

    // -------- weight prep + CSR build (shared by both layers) --------
    (void)hipMemsetAsync(cnt, 0, (size_t)N * sizeof(int), stream);
    csr_count_prep<<<edgeGrid + 128, 256, 0, stream>>>(ei, cnt, W1, W2, wt1, wt2, edgeGrid);
    scan_blocks<<<SCAN_BLOCKS, 256, 0, stream>>>(cnt, off, bsum);
    scan_bsums<<<1, 256, 0, stream>>>(bsum, bpre, &off[NN]);
    scan_add<<<SCAN_BLOCKS, 256, 0, stream>>>(off, bpre, cursor);
    csr_fill<<<edgeGrid, 256, 0, stream>>>(ei, cursor, csrc);

    // ---------------- Layer 1 (H=4, C=32, concat) ----------------
    gemm_fused<4, 1><<<gemmGrid, 256, 0, stream>>>(x, wt1, a_src1, a_dst1, h, als, ald, N);
    aggregate<4, 0><<<aggGrid, 256, 0, stream>>>(off, csrc, h, als, ald, b1, x2);

    // ---------------- Layer 2 (H=1, C=128, mean==identity) ----------------
    gemm_fused<1, 0><<<gemmGrid, 256, 0, stream>>>(x2, wt2, a_src2, a_dst2, h, als, ald, N);
    aggregate<1, 1><<<aggGrid, 256, 0, stream>>>(off, csrc, h, als, ald, b2, d_out);
}

// Round 13
// 265.183 us; speedup vs baseline: 1.0917x; 1.0917x over previous
//
#include <hip/hip_runtime.h>
#include <hip/hip_bf16.h>

#define NN 50000
#define NE 600000
#define SCAN_BLOCKS 196   // ceil(50000/256)

typedef __attribute__((ext_vector_type(8))) short short8v;   // 8 bf16 = 4 VGPRs
typedef __attribute__((ext_vector_type(4))) float float4v;   // MFMA C/D

// Dataset facts (pinned on HW over R3-R8): floats fp32, edges int32, out fp32.
__device__ __forceinline__ float bf2f_u(unsigned short u) {
    union { unsigned int i; float f; } v; v.i = ((unsigned int)u) << 16; return v.f;
}
__device__ __forceinline__ unsigned short f2bf_u(float f) {
    __hip_bfloat16 b = __float2bfloat16(f);
    return *reinterpret_cast<unsigned short*>(&b);
}

// ---------------------------------------------------------------------------
// CSR count (+ folded W-prep in tail blocks).
// ---------------------------------------------------------------------------
__global__ __launch_bounds__(256) void csr_count_prep(const int* __restrict__ ei,
                                                      int* __restrict__ cnt,
                                                      const float* __restrict__ W1,
                                                      const float* __restrict__ W2,
                                                      unsigned short* __restrict__ wt1,
                                                      unsigned short* __restrict__ wt2,
                                                      int edgeBlocks) {
    if ((int)blockIdx.x >= edgeBlocks) {   // W-prep tail: 128 blocks
        int t = (blockIdx.x - edgeBlocks) * 256 + threadIdx.x;   // 0..32767
        const float* src = (t < 16384) ? W1 : W2;
        unsigned short* dst = (t < 16384) ? wt1 : wt2;
        int idx = t & 16383;
        int n = idx >> 7, k = idx & 127;
        dst[idx] = f2bf_u(src[k * 128 + n]);
        return;
    }
    int e = blockIdx.x * 256 + threadIdx.x;
    if (e >= NE) return;
    int d = ei[NE + e];
    d = min(max(d, 0), NN - 1);
    atomicAdd(&cnt[d], 1);
}

__global__ __launch_bounds__(256) void scan_blocks(const int* __restrict__ cnt,
                                                   int* __restrict__ off,
                                                   int* __restrict__ bsum) {
    __shared__ int tmp[256];
    const int t = threadIdx.x;
    int g = blockIdx.x * 256 + t;
    int v = (g < NN) ? cnt[g] : 0;
    tmp[t] = v;
    __syncthreads();
    for (int ofs = 1; ofs < 256; ofs <<= 1) {
        int add = (t >= ofs) ? tmp[t - ofs] : 0;
        __syncthreads();
        tmp[t] += add;
        __syncthreads();
    }
    if (g < NN) off[g] = tmp[t] - v;          // block-local exclusive
    if (t == 255) bsum[blockIdx.x] = tmp[255];
}

__global__ __launch_bounds__(256) void scan_bsums(int* __restrict__ bsum,
                                                  int* __restrict__ bpre,
                                                  int* __restrict__ offNN) {
    __shared__ int tmp[256];
    const int t = threadIdx.x;
    int v = (t < SCAN_BLOCKS) ? bsum[t] : 0;
    tmp[t] = v;
    __syncthreads();
    for (int ofs = 1; ofs < 256; ofs <<= 1) {
        int add = (t >= ofs) ? tmp[t - ofs] : 0;
        __syncthreads();
        tmp[t] += add;
        __syncthreads();
    }
    if (t < SCAN_BLOCKS) bpre[t] = tmp[t] - v;
    if (t == 255) *offNN = tmp[255];          // = NE
}

__global__ __launch_bounds__(256) void scan_add(int* __restrict__ off,
                                                const int* __restrict__ bpre,
                                                int* __restrict__ cursor) {
    int g = blockIdx.x * 256 + threadIdx.x;
    if (g >= NN) return;
    int o = off[g] + bpre[blockIdx.x];
    off[g] = o;
    cursor[g] = o;
}

__global__ __launch_bounds__(256) void csr_fill(const int* __restrict__ ei,
                                                int* __restrict__ cursor,
                                                int* __restrict__ csrc) {
    int e = blockIdx.x * 256 + threadIdx.x;
    if (e >= NE) return;
    int s = ei[e], d = ei[NE + e];
    s = min(max(s, 0), NN - 1);
    d = min(max(d, 0), NN - 1);
    int pos = atomicAdd(&cursor[d], 1);
    csrc[pos] = s;
}

// ---------------------------------------------------------------------------
// MFMA bf16 GEMM + fused attention-logit epilogue (R11, unchanged).
// ---------------------------------------------------------------------------
template<int H, int XF32>
__global__ __launch_bounds__(256) void gemm_fused(const void* __restrict__ X,
                                                  const unsigned short* __restrict__ Wt,
                                                  const float* __restrict__ a_src,
                                                  const float* __restrict__ a_dst,
                                                  unsigned short* __restrict__ Hout,
                                                  float* __restrict__ als,
                                                  float* __restrict__ ald, int n) {
    __shared__ unsigned short Xs[64][136];
    __shared__ unsigned short WtS[128][136];
    __shared__ float as_s[128], ad_s[128];
    const int tid = threadIdx.x;
    const int row0 = blockIdx.x * 64;

    if (tid < 128) { as_s[tid] = a_src[tid]; ad_s[tid] = a_dst[tid]; }
    {   // stage pre-transposed Wt: pure uint4 copies
        const uint4* Wv = (const uint4*)Wt;
#pragma unroll
        for (int i = 0; i < 8; ++i) {
            int lin = tid + 256 * i;              // 0..2047
            int r = lin >> 4, c8 = lin & 15;
            *(uint4*)&WtS[r][c8 * 8] = Wv[lin];
        }
    }
    if (XF32) {
        const float4* Xv = (const float4*)X;
#pragma unroll
        for (int i = 0; i < 8; ++i) {
            int lin = tid + 256 * i;
            int r = lin >> 5, c4 = lin & 31;
            float4 v = make_float4(0.f, 0.f, 0.f, 0.f);
            if (row0 + r < n) v = Xv[(size_t)(row0 + r) * 32 + c4];
            ushort4 o;
            o.x = f2bf_u(v.x); o.y = f2bf_u(v.y); o.z = f2bf_u(v.z); o.w = f2bf_u(v.w);
            *(ushort4*)&Xs[r][c4 * 4] = o;
        }
    } else {
        const uint4* Xv = (const uint4*)X;
#pragma unroll
        for (int i = 0; i < 4; ++i) {
            int lin = tid + 256 * i;
            int r = lin >> 4, c8 = lin & 15;
            uint4 v = make_uint4(0u, 0u, 0u, 0u);
            if (row0 + r < n) v = Xv[(size_t)(row0 + r) * 16 + c8];
            *(uint4*)&Xs[r][c8 * 8] = v;
        }
    }
    __syncthreads();

    const int lane = tid & 63;
    const int wrow = (tid >> 6) * 16;
    const int m = lane & 15, q = lane >> 4;

    float4v acc[8];
#pragma unroll
    for (int ct = 0; ct < 8; ++ct) acc[ct] = (float4v){0.f, 0.f, 0.f, 0.f};

#pragma unroll
    for (int kt = 0; kt < 4; ++kt) {
        short8v af = *(const short8v*)&Xs[wrow + m][kt * 32 + q * 8];
#pragma unroll
        for (int ct = 0; ct < 8; ++ct) {
            short8v bf = *(const short8v*)&WtS[ct * 16 + m][kt * 32 + q * 8];
            acc[ct] = __builtin_amdgcn_mfma_f32_16x16x32_bf16(af, bf, acc[ct], 0, 0, 0);
        }
    }

    // store H (bf16)
#pragma unroll
    for (int ct = 0; ct < 8; ++ct)
#pragma unroll
        for (int r = 0; r < 4; ++r) {
            int grow = row0 + wrow + q * 4 + r;
            if (grow < n) Hout[(size_t)grow * 128 + ct * 16 + m] = f2bf_u(acc[ct][r]);
        }

    // fused als/ald epilogue (fp32 accumulators)
#pragma unroll
    for (int r = 0; r < 4; ++r) {
        int grow = row0 + wrow + q * 4 + r;
        if (H == 4) {
            float ps[4], pd[4];
#pragma unroll
            for (int hd = 0; hd < 4; ++hd) {
                float x0 = acc[2 * hd][r], x1 = acc[2 * hd + 1][r];
                ps[hd] = x0 * as_s[hd * 32 + m] + x1 * as_s[hd * 32 + 16 + m];
                pd[hd] = x0 * ad_s[hd * 32 + m] + x1 * ad_s[hd * 32 + 16 + m];
#pragma unroll
                for (int o = 1; o < 16; o <<= 1) {
                    ps[hd] += __shfl_xor(ps[hd], o);
                    pd[hd] += __shfl_xor(pd[hd], o);
                }
            }
            if (m == 0 && grow < n) {
#pragma unroll
                for (int hd = 0; hd < 4; ++hd) {
                    als[(size_t)grow * 4 + hd] = ps[hd];
                    ald[(size_t)grow * 4 + hd] = pd[hd];
                }
            }
        } else {
            float ps = 0.f, pd = 0.f;
#pragma unroll
            for (int ct = 0; ct < 8; ++ct) {
                float xv = acc[ct][r];
                ps += xv * as_s[ct * 16 + m];
                pd += xv * ad_s[ct * 16 + m];
            }
#pragma unroll
            for (int o = 1; o < 16; o <<= 1) {
                ps += __shfl_xor(ps, o);
                pd += __shfl_xor(pd, o);
            }
            if (m == 0 && grow < n) { als[grow] = ps; ald[grow] = pd; }
        }
    }
}

// ---------------------------------------------------------------------------
// Fused aggregate: ONE wave per node (R12's 2-wave split regressed: sync +
// shorter batches), predicated 8-wide gather rounds (R13): always issue 8
// clamped csrc + 8 h/als gathers; OOB edges use idx=d (cache-hot self row)
// with weight zeroed. No scalar tail -> ceil(deg/8) ~= 2 parallel rounds.
// FINAL=0: +bias, ELU, bf16 x2 out. FINAL=1: +bias, fp32 out. No atomics.
// ---------------------------------------------------------------------------
template<int H, int FINAL>
__global__ __launch_bounds__(256) void aggregate(const int* __restrict__ off,
                                                 const int* __restrict__ csrc,
                                                 const unsigned short* __restrict__ h,
                                                 const float* __restrict__ als,
                                                 const float* __restrict__ ald,
                                                 const float* __restrict__ bias,
                                                 void* __restrict__ out) {
    int wid = (int)((blockIdx.x * 256 + threadIdx.x) >> 6);
    int lane = threadIdx.x & 63;
    if (wid >= NN) return;
    const int d = wid;
    const int hd = (H == 4) ? (lane >> 4) : 0;
    const float aldd = (H == 4) ? ald[(size_t)d * 4 + hd] : ald[d];

    float acc0 = 0.f, acc1 = 0.f, den = 0.f;
    {   // self-loop
        float av = (H == 4) ? als[(size_t)d * 4 + hd] : als[d];
        float v = av + aldd;
        v = v > 0.f ? v : 0.2f * v;
        float ex = __expf(fminf(v, 60.f));
        unsigned int hv = *(const unsigned int*)&h[(size_t)d * 128 + lane * 2];
        acc0 = ex * bf2f_u((unsigned short)hv);
        acc1 = ex * bf2f_u((unsigned short)(hv >> 16));
        den = ex;
    }

    const int beg = off[d], end = off[d + 1];
    for (int j0 = beg; j0 < end; j0 += 8) {
        int idx[8];
#pragma unroll
        for (int k = 0; k < 8; ++k) {
            int jj = min(j0 + k, end - 1);       // end>beg>=0 here, so jj>=0
            idx[k] = csrc[jj];
        }
        unsigned int hv[8];
#pragma unroll
        for (int k = 0; k < 8; ++k)
            hv[k] = *(const unsigned int*)&h[(size_t)idx[k] * 128 + lane * 2];
        float av[8];
#pragma unroll
        for (int k = 0; k < 8; ++k)
            av[k] = (H == 4) ? als[(size_t)idx[k] * 4 + hd] : als[idx[k]];
#pragma unroll
        for (int k = 0; k < 8; ++k) {
            float v = av[k] + aldd;
            v = v > 0.f ? v : 0.2f * v;
            float ex = __expf(fminf(v, 60.f));
            ex = (j0 + k < end) ? ex : 0.f;      // predicate OOB edges
            acc0 += ex * bf2f_u((unsigned short)hv[k]);
            acc1 += ex * bf2f_u((unsigned short)(hv[k] >> 16));
            den += ex;
        }
    }

    const float inv = 1.f / den;
    const int c0 = lane * 2;
    float v0 = acc0 * inv + bias[c0];
    float v1 = acc1 * inv + bias[c0 + 1];
    if (FINAL) {
        ((float2*)out)[(size_t)d * 64 + lane] = make_float2(v0, v1);   // fp32 out
    } else {
        v0 = v0 > 0.f ? v0 : expm1f(v0);
        v1 = v1 > 0.f ? v1 : expm1f(v1);
        unsigned int packed = (unsigned int)f2bf_u(v0) | ((unsigned int)f2bf_u(v1) << 16);
        ((unsigned int*)out)[(size_t)d * 64 + lane] = packed;
    }
}

// ---------------------------------------------------------------------------
extern "C" void kernel_launch(void* const* d_in, const int* in_sizes, int n_in,
                              void* d_out, int out_size, void* d_ws, size_t ws_size,
                              hipStream_t stream) {
    const float* x      = (const float*)d_in[0];
    const int*   ei     = (const int*)d_in[1];
    const float* W1     = (const float*)d_in[2];
    const float* a_src1 = (const float*)d_in[3];
    const float* a_dst1 = (const float*)d_in[4];
    const float* b1     = (const float*)d_in[5];
    const float* W2     = (const float*)d_in[6];
    const float* a_src2 = (const float*)d_in[7];
    const float* a_dst2 = (const float*)d_in[8];
    const float* b2     = (const float*)d_in[9];

    const int N = NN;

    // Workspace: explicit BYTE offsets, every buffer 16B-aligned.
    char* base = (char*)d_ws;
    int*   cnt    = (int*)(base + 0);          //  50000 i
    int*   off    = (int*)(base + 200000);     //  50001 i
    int*   cursor = (int*)(base + 400016);     //  50000 i
    int*   bsum   = (int*)(base + 600016);     //    256 i
    int*   bpre   = (int*)(base + 601040);     //    256 i
    int*   csrc   = (int*)(base + 602064);     // 600000 i
    float* als    = (float*)(base + 3002064);  // 200000 f
    float* ald    = (float*)(base + 3802064);  // 200000 f
    unsigned short* h   = (unsigned short*)(base + 4602064);   // N*128 bf16
    unsigned short* x2  = (unsigned short*)(base + 17402064);  // N*128 bf16
    unsigned short* wt1 = (unsigned short*)(base + 30202064);  // 16384 bf16
    unsigned short* wt2 = (unsigned short*)(base + 30234832);  // 16384 bf16
    // total 30,267,600 B ~= 30.3 MB

    const int gemmGrid = (N + 63) / 64;          // 782
    const int edgeGrid = (NE + 255) / 256;       // 2344
    const int aggGrid  = (N * 64 + 255) / 256;   // 12500 (1 wave/node)

    // -------- weight prep + CSR build (shared by both layers) --------
    (void)hipMemsetAsync(cnt, 0, (size_t)N * sizeof(int), stream);
    csr_count_prep<<<edgeGrid + 128, 256, 0, stream>>>(ei, cnt, W1, W2, wt1, wt2, edgeGrid);
    scan_blocks<<<SCAN_BLOCKS, 256, 0, stream>>>(cnt, off, bsum);
    scan_bsums<<<1, 256, 0, stream>>>(bsum, bpre, &off[NN]);
    scan_add<<<SCAN_BLOCKS, 256, 0, stream>>>(off, bpre, cursor);
    csr_fill<<<edgeGrid, 256, 0, stream>>>(ei, cursor, csrc);

    // ---------------- Layer 1 (H=4, C=32, concat) ----------------
    gemm_fused<4, 1><<<gemmGrid, 256, 0, stream>>>(x, wt1, a_src1, a_dst1, h, als, ald, N);
    aggregate<4, 0><<<aggGrid, 256, 0, stream>>>(off, csrc, h, als, ald, b1, x2);

    // ---------------- Layer 2 (H=1, C=128, mean==identity) ----------------
    gemm_fused<1, 0><<<gemmGrid, 256, 0, stream>>>(x2, wt2, a_src2, a_dst2, h, als, ald, N);
    aggregate<1, 1><<<aggGrid, 256, 0, stream>>>(off, csrc, h, als, ald, b2, d_out);
}

// Round 14
// 262.570 us; speedup vs baseline: 1.1025x; 1.0100x over previous
//
#include <hip/hip_runtime.h>
#include <hip/hip_bf16.h>

#define NN 50000
#define NE 600000

typedef __attribute__((ext_vector_type(8))) short short8v;   // 8 bf16 = 4 VGPRs
typedef __attribute__((ext_vector_type(4))) float float4v;   // MFMA C/D

// Dataset facts (pinned on HW over R3-R8): floats fp32, edges int32, out fp32.
__device__ __forceinline__ float bf2f_u(unsigned short u) {
    union { unsigned int i; float f; } v; v.i = ((unsigned int)u) << 16; return v.f;
}
__device__ __forceinline__ unsigned short f2bf_u(float f) {
    __hip_bfloat16 b = __float2bfloat16(f);
    return *reinterpret_cast<unsigned short*>(&b);
}

// ---------------------------------------------------------------------------
// MFMA bf16 GEMM + fused attention-logit epilogue (R11 core).
// WF32=1: stage W from fp32 with in-LDS transpose (scalar LDS writes; used
// by layer-1 inside mega1 to avoid racing the wt-prep section).
// WF32=0: stage pre-transposed bf16 Wt with uint4 copies.
// XF32: X fp32 (convert on stage) vs bf16.
// C/D layout (m97): col=ct*16+m, row=wrow+q*4+r; head=ct>>1 for H=4.
// ---------------------------------------------------------------------------
template<int H, int XF32, int WF32>
__device__ __forceinline__ void gemm_body(int blk,
                                          const void* __restrict__ X,
                                          const void* __restrict__ Wsrc,
                                          const float* __restrict__ a_src,
                                          const float* __restrict__ a_dst,
                                          unsigned short* __restrict__ Hout,
                                          float* __restrict__ als,
                                          float* __restrict__ ald, int n) {
    __shared__ unsigned short Xs[64][136];
    __shared__ unsigned short WtS[128][136];
    __shared__ float as_s[128], ad_s[128];
    const int tid = threadIdx.x;
    const int row0 = blk * 64;

    if (tid < 128) { as_s[tid] = a_src[tid]; ad_s[tid] = a_dst[tid]; }
    if (WF32) {   // W fp32 [k][n] -> WtS[n][k] (convert + transpose)
        const float4* Wv = (const float4*)Wsrc;
#pragma unroll
        for (int i = 0; i < 16; ++i) {
            int lin = tid + 256 * i;              // 0..4095
            int r = lin >> 5, c4 = lin & 31;      // k-row r, cols 4c4..
            float4 v = Wv[lin];
            WtS[c4 * 4 + 0][r] = f2bf_u(v.x);
            WtS[c4 * 4 + 1][r] = f2bf_u(v.y);
            WtS[c4 * 4 + 2][r] = f2bf_u(v.z);
            WtS[c4 * 4 + 3][r] = f2bf_u(v.w);
        }
    } else {      // pre-transposed bf16 Wt: pure uint4 copies
        const uint4* Wv = (const uint4*)Wsrc;
#pragma unroll
        for (int i = 0; i < 8; ++i) {
            int lin = tid + 256 * i;              // 0..2047
            int r = lin >> 4, c8 = lin & 15;
            *(uint4*)&WtS[r][c8 * 8] = Wv[lin];
        }
    }
    if (XF32) {
        const float4* Xv = (const float4*)X;
#pragma unroll
        for (int i = 0; i < 8; ++i) {
            int lin = tid + 256 * i;
            int r = lin >> 5, c4 = lin & 31;
            float4 v = make_float4(0.f, 0.f, 0.f, 0.f);
            if (row0 + r < n) v = Xv[(size_t)(row0 + r) * 32 + c4];
            ushort4 o;
            o.x = f2bf_u(v.x); o.y = f2bf_u(v.y); o.z = f2bf_u(v.z); o.w = f2bf_u(v.w);
            *(ushort4*)&Xs[r][c4 * 4] = o;
        }
    } else {
        const uint4* Xv = (const uint4*)X;
#pragma unroll
        for (int i = 0; i < 4; ++i) {
            int lin = tid + 256 * i;
            int r = lin >> 4, c8 = lin & 15;
            uint4 v = make_uint4(0u, 0u, 0u, 0u);
            if (row0 + r < n) v = Xv[(size_t)(row0 + r) * 16 + c8];
            *(uint4*)&Xs[r][c8 * 8] = v;
        }
    }
    __syncthreads();

    const int lane = tid & 63;
    const int wrow = (tid >> 6) * 16;
    const int m = lane & 15, q = lane >> 4;

    float4v acc[8];
#pragma unroll
    for (int ct = 0; ct < 8; ++ct) acc[ct] = (float4v){0.f, 0.f, 0.f, 0.f};

#pragma unroll
    for (int kt = 0; kt < 4; ++kt) {
        short8v af = *(const short8v*)&Xs[wrow + m][kt * 32 + q * 8];
#pragma unroll
        for (int ct = 0; ct < 8; ++ct) {
            short8v bf = *(const short8v*)&WtS[ct * 16 + m][kt * 32 + q * 8];
            acc[ct] = __builtin_amdgcn_mfma_f32_16x16x32_bf16(af, bf, acc[ct], 0, 0, 0);
        }
    }

    // store H (bf16)
#pragma unroll
    for (int ct = 0; ct < 8; ++ct)
#pragma unroll
        for (int r = 0; r < 4; ++r) {
            int grow = row0 + wrow + q * 4 + r;
            if (grow < n) Hout[(size_t)grow * 128 + ct * 16 + m] = f2bf_u(acc[ct][r]);
        }

    // fused als/ald epilogue (fp32 accumulators)
#pragma unroll
    for (int r = 0; r < 4; ++r) {
        int grow = row0 + wrow + q * 4 + r;
        if (H == 4) {
            float ps[4], pd[4];
#pragma unroll
            for (int hd = 0; hd < 4; ++hd) {
                float x0 = acc[2 * hd][r], x1 = acc[2 * hd + 1][r];
                ps[hd] = x0 * as_s[hd * 32 + m] + x1 * as_s[hd * 32 + 16 + m];
                pd[hd] = x0 * ad_s[hd * 32 + m] + x1 * ad_s[hd * 32 + 16 + m];
#pragma unroll
                for (int o = 1; o < 16; o <<= 1) {
                    ps[hd] += __shfl_xor(ps[hd], o);
                    pd[hd] += __shfl_xor(pd[hd], o);
                }
            }
            if (m == 0 && grow < n) {
#pragma unroll
                for (int hd = 0; hd < 4; ++hd) {
                    als[(size_t)grow * 4 + hd] = ps[hd];
                    ald[(size_t)grow * 4 + hd] = pd[hd];
                }
            }
        } else {
            float ps = 0.f, pd = 0.f;
#pragma unroll
            for (int ct = 0; ct < 8; ++ct) {
                float xv = acc[ct][r];
                ps += xv * as_s[ct * 16 + m];
                pd += xv * ad_s[ct * 16 + m];
            }
#pragma unroll
            for (int o = 1; o < 16; o <<= 1) {
                ps += __shfl_xor(ps, o);
                pd += __shfl_xor(pd, o);
            }
            if (m == 0 && grow < n) { als[grow] = ps; ald[grow] = pd; }
        }
    }
}

// ---------------------------------------------------------------------------
// MEGA kernel: gemm1 (stages W1 itself, WF32=1) + csr_count + wt2-prep.
// All sections independent -> count/prep hide under the GEMM (R14).
// ---------------------------------------------------------------------------
__global__ __launch_bounds__(256) void mega1(const float* __restrict__ x,
                                             const float* __restrict__ W1,
                                             const float* __restrict__ a_src1,
                                             const float* __restrict__ a_dst1,
                                             unsigned short* __restrict__ h,
                                             float* __restrict__ als,
                                             float* __restrict__ ald,
                                             const int* __restrict__ ei,
                                             int* __restrict__ cnt,
                                             const float* __restrict__ W2,
                                             unsigned short* __restrict__ wt2,
                                             int gemmGrid, int edgeBlocks) {
    int b = blockIdx.x;
    if (b < gemmGrid) {
        gemm_body<4, 1, 1>(b, x, W1, a_src1, a_dst1, h, als, ald, NN);
        return;
    }
    b -= gemmGrid;
    if (b < edgeBlocks) {
        int e = b * 256 + threadIdx.x;
        if (e >= NE) return;
        int d = ei[NE + e];
        d = min(max(d, 0), NN - 1);
        atomicAdd(&cnt[d], 1);
        return;
    }
    b -= edgeBlocks;
    {   // wt2-prep: fp32 W2[k][n] -> bf16 wt2[n][k]  (64 blocks)
        int t = b * 256 + threadIdx.x;            // 0..16383
        int n = t >> 7, k = t & 127;
        wt2[t] = f2bf_u(W2[k * 128 + n]);
    }
}

// Layer-2 GEMM standalone wrapper (wt2 ready after mega1).
__global__ __launch_bounds__(256) void gemm2(const unsigned short* __restrict__ x2,
                                             const unsigned short* __restrict__ wt2,
                                             const float* __restrict__ a_src2,
                                             const float* __restrict__ a_dst2,
                                             unsigned short* __restrict__ h,
                                             float* __restrict__ als,
                                             float* __restrict__ ald) {
    gemm_body<1, 0, 0>(blockIdx.x, x2, wt2, a_src2, a_dst2, h, als, ald, NN);
}

// ---------------------------------------------------------------------------
// CSR alloc: ONE kernel replaces the 3-stage scan (R14). Offsets need NOT be
// monotone in node id -- each node just needs a unique contiguous range.
// Block-local inclusive scan + one atomicAdd for the block base.
// ---------------------------------------------------------------------------
__global__ __launch_bounds__(256) void csr_alloc(const int* __restrict__ cnt,
                                                 int* __restrict__ off,
                                                 int* __restrict__ cursor,
                                                 int* __restrict__ gbase) {
    __shared__ int tmp[256];
    __shared__ int blockBase;
    const int t = threadIdx.x;
    int g = blockIdx.x * 256 + t;
    int v = (g < NN) ? cnt[g] : 0;
    tmp[t] = v;
    __syncthreads();
    for (int ofs = 1; ofs < 256; ofs <<= 1) {
        int add = (t >= ofs) ? tmp[t - ofs] : 0;
        __syncthreads();
        tmp[t] += add;
        __syncthreads();
    }
    if (t == 255) blockBase = atomicAdd(gbase, tmp[255]);
    __syncthreads();
    if (g < NN) {
        int o = blockBase + tmp[t] - v;
        off[g] = o;
        cursor[g] = o;
    }
}

__global__ __launch_bounds__(256) void csr_fill(const int* __restrict__ ei,
                                                int* __restrict__ cursor,
                                                int* __restrict__ csrc) {
    int e = blockIdx.x * 256 + threadIdx.x;
    if (e >= NE) return;
    int s = ei[e], d = ei[NE + e];
    s = min(max(s, 0), NN - 1);
    d = min(max(d, 0), NN - 1);
    int pos = atomicAdd(&cursor[d], 1);
    csrc[pos] = s;
}

// ---------------------------------------------------------------------------
// Fused aggregate (R13): one wave per node, predicated 8-wide gather rounds.
// end = off[d] + cnt[d] (offsets not monotone after csr_alloc).
// ---------------------------------------------------------------------------
template<int H, int FINAL>
__global__ __launch_bounds__(256) void aggregate(const int* __restrict__ off,
                                                 const int* __restrict__ cnt,
                                                 const int* __restrict__ csrc,
                                                 const unsigned short* __restrict__ h,
                                                 const float* __restrict__ als,
                                                 const float* __restrict__ ald,
                                                 const float* __restrict__ bias,
                                                 void* __restrict__ out) {
    int wid = (int)((blockIdx.x * 256 + threadIdx.x) >> 6);
    int lane = threadIdx.x & 63;
    if (wid >= NN) return;
    const int d = wid;
    const int hd = (H == 4) ? (lane >> 4) : 0;
    const float aldd = (H == 4) ? ald[(size_t)d * 4 + hd] : ald[d];

    float acc0 = 0.f, acc1 = 0.f, den = 0.f;
    {   // self-loop
        float av = (H == 4) ? als[(size_t)d * 4 + hd] : als[d];
        float v = av + aldd;
        v = v > 0.f ? v : 0.2f * v;
        float ex = __expf(fminf(v, 60.f));
        unsigned int hv = *(const unsigned int*)&h[(size_t)d * 128 + lane * 2];
        acc0 = ex * bf2f_u((unsigned short)hv);
        acc1 = ex * bf2f_u((unsigned short)(hv >> 16));
        den = ex;
    }

    const int beg = off[d];
    const int end = beg + cnt[d];
    for (int j0 = beg; j0 < end; j0 += 8) {
        int idx[8];
#pragma unroll
        for (int k = 0; k < 8; ++k) {
            int jj = min(j0 + k, end - 1);
            idx[k] = csrc[jj];
        }
        unsigned int hv[8];
#pragma unroll
        for (int k = 0; k < 8; ++k)
            hv[k] = *(const unsigned int*)&h[(size_t)idx[k] * 128 + lane * 2];
        float av[8];
#pragma unroll
        for (int k = 0; k < 8; ++k)
            av[k] = (H == 4) ? als[(size_t)idx[k] * 4 + hd] : als[idx[k]];
#pragma unroll
        for (int k = 0; k < 8; ++k) {
            float v = av[k] + aldd;
            v = v > 0.f ? v : 0.2f * v;
            float ex = __expf(fminf(v, 60.f));
            ex = (j0 + k < end) ? ex : 0.f;      // predicate OOB edges
            acc0 += ex * bf2f_u((unsigned short)hv[k]);
            acc1 += ex * bf2f_u((unsigned short)(hv[k] >> 16));
            den += ex;
        }
    }

    const float inv = 1.f / den;
    const int c0 = lane * 2;
    float v0 = acc0 * inv + bias[c0];
    float v1 = acc1 * inv + bias[c0 + 1];
    if (FINAL) {
        ((float2*)out)[(size_t)d * 64 + lane] = make_float2(v0, v1);   // fp32 out
    } else {
        v0 = v0 > 0.f ? v0 : expm1f(v0);
        v1 = v1 > 0.f ? v1 : expm1f(v1);
        unsigned int packed = (unsigned int)f2bf_u(v0) | ((unsigned int)f2bf_u(v1) << 16);
        ((unsigned int*)out)[(size_t)d * 64 + lane] = packed;
    }
}

// ---------------------------------------------------------------------------
extern "C" void kernel_launch(void* const* d_in, const int* in_sizes, int n_in,
                              void* d_out, int out_size, void* d_ws, size_t ws_size,
                              hipStream_t stream) {
    const float* x      = (const float*)d_in[0];
    const int*   ei     = (const int*)d_in[1];
    const float* W1     = (const float*)d_in[2];
    const float* a_src1 = (const float*)d_in[3];
    const float* a_dst1 = (const float*)d_in[4];
    const float* b1     = (const float*)d_in[5];
    const float* W2     = (const float*)d_in[6];
    const float* a_src2 = (const float*)d_in[7];
    const float* a_dst2 = (const float*)d_in[8];
    const float* b2     = (const float*)d_in[9];

    const int N = NN;

    // Workspace: explicit BYTE offsets, every buffer 16B-aligned.
    char* base = (char*)d_ws;
    int*   cnt    = (int*)(base + 0);          //  50000 i
    int*   off    = (int*)(base + 200000);     //  50000 i
    int*   cursor = (int*)(base + 400016);     //  50000 i
    int*   gbase  = (int*)(base + 600016);     //      1 i
    int*   csrc   = (int*)(base + 602064);     // 600000 i
    float* als    = (float*)(base + 3002064);  // 200000 f
    float* ald    = (float*)(base + 3802064);  // 200000 f
    unsigned short* h   = (unsigned short*)(base + 4602064);   // N*128 bf16
    unsigned short* x2  = (unsigned short*)(base + 17402064);  // N*128 bf16
    unsigned short* wt2 = (unsigned short*)(base + 30202064);  // 16384 bf16
    // total ~30.24 MB

    const int gemmGrid  = (N + 63) / 64;          // 782
    const int edgeGrid  = (NE + 255) / 256;       // 2344
    const int allocGrid = (N + 255) / 256;        // 196
    const int aggGrid   = (N * 64 + 255) / 256;   // 12500

    (void)hipMemsetAsync(cnt, 0, 200000, stream);
    (void)hipMemsetAsync(gbase, 0, 4, stream);
    // mega: gemm1 + csr_count + wt2-prep (64 prep blocks), all independent
    mega1<<<gemmGrid + edgeGrid + 64, 256, 0, stream>>>(
        x, W1, a_src1, a_dst1, h, als, ald, ei, cnt, W2, wt2,
        gemmGrid, edgeGrid);
    csr_alloc<<<allocGrid, 256, 0, stream>>>(cnt, off, cursor, gbase);
    csr_fill<<<edgeGrid, 256, 0, stream>>>(ei, cursor, csrc);

    aggregate<4, 0><<<aggGrid, 256, 0, stream>>>(off, cnt, csrc, h, als, ald, b1, x2);
    gemm2<<<gemmGrid, 256, 0, stream>>>(x2, wt2, a_src2, a_dst2, h, als, ald);
    aggregate<1, 1><<<aggGrid, 256, 0, stream>>>(off, cnt, csrc, h, als, ald, b2, d_out);
}

// Round 15
// 258.628 us; speedup vs baseline: 1.1193x; 1.0152x over previous
//
#include <hip/hip_runtime.h>
#include <hip/hip_bf16.h>

#define NN 50000
#define NE 600000

typedef __attribute__((ext_vector_type(8))) short short8v;   // 8 bf16 = 4 VGPRs
typedef __attribute__((ext_vector_type(4))) float float4v;   // MFMA C/D

// Dataset facts (pinned on HW over R3-R8): floats fp32, edges int32, out fp32.
__device__ __forceinline__ float bf2f_u(unsigned short u) {
    union { unsigned int i; float f; } v; v.i = ((unsigned int)u) << 16; return v.f;
}
__device__ __forceinline__ unsigned short f2bf_u(float f) {
    __hip_bfloat16 b = __float2bfloat16(f);
    return *reinterpret_cast<unsigned short*>(&b);
}

// ---------------------------------------------------------------------------
// W prep: fp32 W[k][n] -> bf16 Wt[n][k], both weights. Runs BEFORE mega1.
// (R14 lesson: in-GEMM fp32 W transpose = 16-way LDS bank conflicts,
//  6.46M SQ_LDS_BANK_CONFLICT, mega1 57.6 us. Pre-transposing kills them.)
// ---------------------------------------------------------------------------
__global__ __launch_bounds__(256) void prep_wt(const float* __restrict__ W1,
                                               const float* __restrict__ W2,
                                               unsigned short* __restrict__ wt1,
                                               unsigned short* __restrict__ wt2) {
    int t = blockIdx.x * 256 + threadIdx.x;        // 0..32767
    const float* src = (t < 16384) ? W1 : W2;
    unsigned short* dst = (t < 16384) ? wt1 : wt2;
    int idx = t & 16383;
    int n = idx >> 7, k = idx & 127;
    dst[idx] = f2bf_u(src[k * 128 + n]);
}

// ---------------------------------------------------------------------------
// MFMA bf16 GEMM + fused attention-logit epilogue (R11 core).
// Wt pre-transposed bf16 [n][k]: staged with pure uint4 copies.
// XF32=1: X fp32 (convert on stage); 0: X bf16.
// C/D layout (m97): col=ct*16+m, row=wrow+q*4+r; head=ct>>1 for H=4.
// ---------------------------------------------------------------------------
template<int H, int XF32>
__device__ __forceinline__ void gemm_body(int blk,
                                          const void* __restrict__ X,
                                          const unsigned short* __restrict__ Wt,
                                          const float* __restrict__ a_src,
                                          const float* __restrict__ a_dst,
                                          unsigned short* __restrict__ Hout,
                                          float* __restrict__ als,
                                          float* __restrict__ ald, int n) {
    __shared__ unsigned short Xs[64][136];
    __shared__ unsigned short WtS[128][136];
    __shared__ float as_s[128], ad_s[128];
    const int tid = threadIdx.x;
    const int row0 = blk * 64;

    if (tid < 128) { as_s[tid] = a_src[tid]; ad_s[tid] = a_dst[tid]; }
    {   // stage pre-transposed Wt: pure uint4 copies (conflict-free)
        const uint4* Wv = (const uint4*)Wt;
#pragma unroll
        for (int i = 0; i < 8; ++i) {
            int lin = tid + 256 * i;              // 0..2047
            int r = lin >> 4, c8 = lin & 15;
            *(uint4*)&WtS[r][c8 * 8] = Wv[lin];
        }
    }
    if (XF32) {
        const float4* Xv = (const float4*)X;
#pragma unroll
        for (int i = 0; i < 8; ++i) {
            int lin = tid + 256 * i;
            int r = lin >> 5, c4 = lin & 31;
            float4 v = make_float4(0.f, 0.f, 0.f, 0.f);
            if (row0 + r < n) v = Xv[(size_t)(row0 + r) * 32 + c4];
            ushort4 o;
            o.x = f2bf_u(v.x); o.y = f2bf_u(v.y); o.z = f2bf_u(v.z); o.w = f2bf_u(v.w);
            *(ushort4*)&Xs[r][c4 * 4] = o;
        }
    } else {
        const uint4* Xv = (const uint4*)X;
#pragma unroll
        for (int i = 0; i < 4; ++i) {
            int lin = tid + 256 * i;
            int r = lin >> 4, c8 = lin & 15;
            uint4 v = make_uint4(0u, 0u, 0u, 0u);
            if (row0 + r < n) v = Xv[(size_t)(row0 + r) * 16 + c8];
            *(uint4*)&Xs[r][c8 * 8] = v;
        }
    }
    __syncthreads();

    const int lane = tid & 63;
    const int wrow = (tid >> 6) * 16;
    const int m = lane & 15, q = lane >> 4;

    float4v acc[8];
#pragma unroll
    for (int ct = 0; ct < 8; ++ct) acc[ct] = (float4v){0.f, 0.f, 0.f, 0.f};

#pragma unroll
    for (int kt = 0; kt < 4; ++kt) {
        short8v af = *(const short8v*)&Xs[wrow + m][kt * 32 + q * 8];
#pragma unroll
        for (int ct = 0; ct < 8; ++ct) {
            short8v bf = *(const short8v*)&WtS[ct * 16 + m][kt * 32 + q * 8];
            acc[ct] = __builtin_amdgcn_mfma_f32_16x16x32_bf16(af, bf, acc[ct], 0, 0, 0);
        }
    }

    // store H (bf16)
#pragma unroll
    for (int ct = 0; ct < 8; ++ct)
#pragma unroll
        for (int r = 0; r < 4; ++r) {
            int grow = row0 + wrow + q * 4 + r;
            if (grow < n) Hout[(size_t)grow * 128 + ct * 16 + m] = f2bf_u(acc[ct][r]);
        }

    // fused als/ald epilogue (fp32 accumulators)
#pragma unroll
    for (int r = 0; r < 4; ++r) {
        int grow = row0 + wrow + q * 4 + r;
        if (H == 4) {
            float ps[4], pd[4];
#pragma unroll
            for (int hd = 0; hd < 4; ++hd) {
                float x0 = acc[2 * hd][r], x1 = acc[2 * hd + 1][r];
                ps[hd] = x0 * as_s[hd * 32 + m] + x1 * as_s[hd * 32 + 16 + m];
                pd[hd] = x0 * ad_s[hd * 32 + m] + x1 * ad_s[hd * 32 + 16 + m];
#pragma unroll
                for (int o = 1; o < 16; o <<= 1) {
                    ps[hd] += __shfl_xor(ps[hd], o);
                    pd[hd] += __shfl_xor(pd[hd], o);
                }
            }
            if (m == 0 && grow < n) {
#pragma unroll
                for (int hd = 0; hd < 4; ++hd) {
                    als[(size_t)grow * 4 + hd] = ps[hd];
                    ald[(size_t)grow * 4 + hd] = pd[hd];
                }
            }
        } else {
            float ps = 0.f, pd = 0.f;
#pragma unroll
            for (int ct = 0; ct < 8; ++ct) {
                float xv = acc[ct][r];
                ps += xv * as_s[ct * 16 + m];
                pd += xv * ad_s[ct * 16 + m];
            }
#pragma unroll
            for (int o = 1; o < 16; o <<= 1) {
                ps += __shfl_xor(ps, o);
                pd += __shfl_xor(pd, o);
            }
            if (m == 0 && grow < n) { als[grow] = ps; ald[grow] = pd; }
        }
    }
}

// ---------------------------------------------------------------------------
// MEGA kernel: gemm1 (reads pre-transposed wt1) + csr_count. Independent
// sections -> count hides under the GEMM.
// ---------------------------------------------------------------------------
__global__ __launch_bounds__(256) void mega1(const float* __restrict__ x,
                                             const unsigned short* __restrict__ wt1,
                                             const float* __restrict__ a_src1,
                                             const float* __restrict__ a_dst1,
                                             unsigned short* __restrict__ h,
                                             float* __restrict__ als,
                                             float* __restrict__ ald,
                                             const int* __restrict__ ei,
                                             int* __restrict__ cnt,
                                             int gemmGrid) {
    int b = blockIdx.x;
    if (b < gemmGrid) {
        gemm_body<4, 1>(b, x, wt1, a_src1, a_dst1, h, als, ald, NN);
        return;
    }
    b -= gemmGrid;
    int e = b * 256 + threadIdx.x;
    if (e >= NE) return;
    int d = ei[NE + e];
    d = min(max(d, 0), NN - 1);
    atomicAdd(&cnt[d], 1);
}

// Layer-2 GEMM standalone wrapper.
__global__ __launch_bounds__(256) void gemm2(const unsigned short* __restrict__ x2,
                                             const unsigned short* __restrict__ wt2,
                                             const float* __restrict__ a_src2,
                                             const float* __restrict__ a_dst2,
                                             unsigned short* __restrict__ h,
                                             float* __restrict__ als,
                                             float* __restrict__ ald) {
    gemm_body<1, 0>(blockIdx.x, x2, wt2, a_src2, a_dst2, h, als, ald, NN);
}

// ---------------------------------------------------------------------------
// CSR alloc: ONE kernel (R14). Offsets need not be monotone in node id --
// block-local scan + one atomicAdd for the block base.
// ---------------------------------------------------------------------------
__global__ __launch_bounds__(256) void csr_alloc(const int* __restrict__ cnt,
                                                 int* __restrict__ off,
                                                 int* __restrict__ cursor,
                                                 int* __restrict__ gbase) {
    __shared__ int tmp[256];
    __shared__ int blockBase;
    const int t = threadIdx.x;
    int g = blockIdx.x * 256 + t;
    int v = (g < NN) ? cnt[g] : 0;
    tmp[t] = v;
    __syncthreads();
    for (int ofs = 1; ofs < 256; ofs <<= 1) {
        int add = (t >= ofs) ? tmp[t - ofs] : 0;
        __syncthreads();
        tmp[t] += add;
        __syncthreads();
    }
    if (t == 255) blockBase = atomicAdd(gbase, tmp[255]);
    __syncthreads();
    if (g < NN) {
        int o = blockBase + tmp[t] - v;
        off[g] = o;
        cursor[g] = o;
    }
}

__global__ __launch_bounds__(256) void csr_fill(const int* __restrict__ ei,
                                                int* __restrict__ cursor,
                                                int* __restrict__ csrc) {
    int e = blockIdx.x * 256 + threadIdx.x;
    if (e >= NE) return;
    int s = ei[e], d = ei[NE + e];
    s = min(max(s, 0), NN - 1);
    d = min(max(d, 0), NN - 1);
    int pos = atomicAdd(&cursor[d], 1);
    csrc[pos] = s;
}

// ---------------------------------------------------------------------------
// Fused aggregate (R13): one wave per node, predicated 8-wide gather rounds.
// end = off[d] + cnt[d].
// ---------------------------------------------------------------------------
template<int H, int FINAL>
__global__ __launch_bounds__(256) void aggregate(const int* __restrict__ off,
                                                 const int* __restrict__ cnt,
                                                 const int* __restrict__ csrc,
                                                 const unsigned short* __restrict__ h,
                                                 const float* __restrict__ als,
                                                 const float* __restrict__ ald,
                                                 const float* __restrict__ bias,
                                                 void* __restrict__ out) {
    int wid = (int)((blockIdx.x * 256 + threadIdx.x) >> 6);
    int lane = threadIdx.x & 63;
    if (wid >= NN) return;
    const int d = wid;
    const int hd = (H == 4) ? (lane >> 4) : 0;
    const float aldd = (H == 4) ? ald[(size_t)d * 4 + hd] : ald[d];

    float acc0 = 0.f, acc1 = 0.f, den = 0.f;
    {   // self-loop
        float av = (H == 4) ? als[(size_t)d * 4 + hd] : als[d];
        float v = av + aldd;
        v = v > 0.f ? v : 0.2f * v;
        float ex = __expf(fminf(v, 60.f));
        unsigned int hv = *(const unsigned int*)&h[(size_t)d * 128 + lane * 2];
        acc0 = ex * bf2f_u((unsigned short)hv);
        acc1 = ex * bf2f_u((unsigned short)(hv >> 16));
        den = ex;
    }

    const int beg = off[d];
    const int end = beg + cnt[d];
    for (int j0 = beg; j0 < end; j0 += 8) {
        int idx[8];
#pragma unroll
        for (int k = 0; k < 8; ++k) {
            int jj = min(j0 + k, end - 1);
            idx[k] = csrc[jj];
        }
        unsigned int hv[8];
#pragma unroll
        for (int k = 0; k < 8; ++k)
            hv[k] = *(const unsigned int*)&h[(size_t)idx[k] * 128 + lane * 2];
        float av[8];
#pragma unroll
        for (int k = 0; k < 8; ++k)
            av[k] = (H == 4) ? als[(size_t)idx[k] * 4 + hd] : als[idx[k]];
#pragma unroll
        for (int k = 0; k < 8; ++k) {
            float v = av[k] + aldd;
            v = v > 0.f ? v : 0.2f * v;
            float ex = __expf(fminf(v, 60.f));
            ex = (j0 + k < end) ? ex : 0.f;      // predicate OOB edges
            acc0 += ex * bf2f_u((unsigned short)hv[k]);
            acc1 += ex * bf2f_u((unsigned short)(hv[k] >> 16));
            den += ex;
        }
    }

    const float inv = 1.f / den;
    const int c0 = lane * 2;
    float v0 = acc0 * inv + bias[c0];
    float v1 = acc1 * inv + bias[c0 + 1];
    if (FINAL) {
        ((float2*)out)[(size_t)d * 64 + lane] = make_float2(v0, v1);   // fp32 out
    } else {
        v0 = v0 > 0.f ? v0 : expm1f(v0);
        v1 = v1 > 0.f ? v1 : expm1f(v1);
        unsigned int packed = (unsigned int)f2bf_u(v0) | ((unsigned int)f2bf_u(v1) << 16);
        ((unsigned int*)out)[(size_t)d * 64 + lane] = packed;
    }
}

// ---------------------------------------------------------------------------
extern "C" void kernel_launch(void* const* d_in, const int* in_sizes, int n_in,
                              void* d_out, int out_size, void* d_ws, size_t ws_size,
                              hipStream_t stream) {
    const float* x      = (const float*)d_in[0];
    const int*   ei     = (const int*)d_in[1];
    const float* W1     = (const float*)d_in[2];
    const float* a_src1 = (const float*)d_in[3];
    const float* a_dst1 = (const float*)d_in[4];
    const float* b1     = (const float*)d_in[5];
    const float* W2     = (const float*)d_in[6];
    const float* a_src2 = (const float*)d_in[7];
    const float* a_dst2 = (const float*)d_in[8];
    const float* b2     = (const float*)d_in[9];

    const int N = NN;

    // Workspace: explicit BYTE offsets, every buffer 16B-aligned.
    // cnt and gbase adjacent -> single memset clears both.
    char* base = (char*)d_ws;
    int*   cnt    = (int*)(base + 0);          //  50000 i [0, 200000)
    int*   gbase  = (int*)(base + 200000);     //      1 i
    int*   off    = (int*)(base + 200016);     //  50000 i
    int*   cursor = (int*)(base + 400016);     //  50000 i
    int*   csrc   = (int*)(base + 602064);     // 600000 i
    float* als    = (float*)(base + 3002064);  // 200000 f
    float* ald    = (float*)(base + 3802064);  // 200000 f
    unsigned short* h   = (unsigned short*)(base + 4602064);   // N*128 bf16
    unsigned short* x2  = (unsigned short*)(base + 17402064);  // N*128 bf16
    unsigned short* wt1 = (unsigned short*)(base + 30202064);  // 16384 bf16
    unsigned short* wt2 = (unsigned short*)(base + 30234832);  // 16384 bf16
    // total ~30.27 MB

    const int gemmGrid  = (N + 63) / 64;          // 782
    const int edgeGrid  = (NE + 255) / 256;       // 2344
    const int allocGrid = (N + 255) / 256;        // 196
    const int aggGrid   = (N * 64 + 255) / 256;   // 12500

    (void)hipMemsetAsync(cnt, 0, 200016, stream);            // cnt + gbase
    prep_wt<<<128, 256, 0, stream>>>(W1, W2, wt1, wt2);      // ~3 us
    mega1<<<gemmGrid + edgeGrid, 256, 0, stream>>>(
        x, wt1, a_src1, a_dst1, h, als, ald, ei, cnt, gemmGrid);
    csr_alloc<<<allocGrid, 256, 0, stream>>>(cnt, off, cursor, gbase);
    csr_fill<<<edgeGrid, 256, 0, stream>>>(ei, cursor, csrc);

    aggregate<4, 0><<<aggGrid, 256, 0, stream>>>(off, cnt, csrc, h, als, ald, b1, x2);
    gemm2<<<gemmGrid, 256, 0, stream>>>(x2, wt2, a_src2, a_dst2, h, als, ald);
    aggregate<1, 1><<<aggGrid, 256, 0, stream>>>(off, cnt, csrc, h, als, ald, b2, d_out);
}